// Round 4
// baseline (397.590 us; speedup 1.0000x reference)
//
#include <hip/hip_runtime.h>
#include <stdint.h>

#define B_   32
#define CIN  128
#define HH   96
#define WW   96
#define HW   (HH*WW)        // 9216
#define NPIX (B_*HW)        // 294912
#define AROWS 144
#define APAD  136           // bf16 elems per row in LDS (272 B, +8 pad)
#define SCALE 0.08838834764831845f  // 1/sqrt(128)
#define ESW   100           // epilogue tile row stride (bank-spread)
#define NT    3             // pixel tiles per K2 block

typedef __attribute__((ext_vector_type(8))) short bf16x8;
typedef __attribute__((ext_vector_type(4))) float f32x4;

__device__ inline unsigned short f2bf(float f) {
    unsigned int u = __float_as_uint(f);
    u += 0x7fffu + ((u >> 16) & 1u);   // round-to-nearest-even
    return (unsigned short)(u >> 16);
}

// ---------------- K1: Abuf[144][128] = [W^T W ; v ; 0], vbuf, sbuf ----------
__global__ __launch_bounds__(128) void k1_prep(
    const float* __restrict__ Wm, const float* __restrict__ bias,
    unsigned short* __restrict__ Abuf, float* __restrict__ vbuf,
    float* __restrict__ sbuf) {
    int r = blockIdx.x;      // 0..143
    int c = threadIdx.x;     // 0..127
    float acc = 0.f;
    if (r < 128) {
        for (int f = 0; f < 128; ++f)
            acc += Wm[f * 128 + r] * Wm[f * 128 + c];
    } else if (r == 128) {
        for (int f = 0; f < 128; ++f)
            acc += Wm[f * 128 + c] * bias[f];
        vbuf[c] = acc;
        if (c == 0) {
            float s = 0.f;
            for (int f = 0; f < 128; ++f) s += bias[f] * bias[f];
            sbuf[0] = s;
        }
    }
    Abuf[r * 128 + c] = f2bf(acc);
}

// ---- K2: y2[seg][b][hw][8ch] = (M a2 + v) bf16 planar; z2 = v.a2 + s ------
// B-frags (pixels) direct from global in registers; A = M from LDS.
// LDS 39168 B -> 4 blocks/CU; one barrier total; no inter-tile syncs.
__global__ __launch_bounds__(256, 4) void k2_proj(
    const float* __restrict__ a2, const unsigned short* __restrict__ Abuf,
    const float* __restrict__ vbuf, const float* __restrict__ sbuf,
    unsigned short* __restrict__ y2, float* __restrict__ z2) {
    __shared__ __align__(16) unsigned short Asm[AROWS * APAD];  // 39168 B

    const int t = threadIdx.x;
    // stage A once (144 rows x 128 bf16 = 2304 x 16B)
    for (int i = t; i < 2304; i += 256) {
        int row = i >> 4, seg = i & 15;
        *(uint4*)(&Asm[row * APAD + seg * 8]) =
            *(const uint4*)(Abuf + row * 128 + seg * 8);
    }
    __syncthreads();

    const int wv = t >> 6;
    const int l = t & 63;
    const int li = l & 15;       // pixel within 16
    const int hi = l >> 4;       // k-subchunk selector
    const int rbase = hi * 4;    // c_out sub-base in D

    // v-row preload (tile-invariant)
    float vr[8][4];
#pragma unroll
    for (int m = 0; m < 8; ++m)
#pragma unroll
        for (int q = 0; q < 4; ++q)
            vr[m][q] = vbuf[m * 16 + rbase + q];
    const float sv = sbuf[0];

    int tile = blockIdx.x * NT;
    for (int tt = 0; tt < NT; ++tt, ++tile) {
        const int b = tile / 144;
        const int hw0 = (tile - b * 144) * 64;
        const int px = hw0 + wv * 16 + li;
        const float* ap = a2 + (size_t)b * (CIN * HW) + px;

        // B-frags from global: lane reads 8 channel-strided f32 per kk
        bf16x8 bfr[4];
#pragma unroll
        for (int kk = 0; kk < 4; ++kk) {
            union { bf16x8 v; unsigned short s[8]; } u;
#pragma unroll
            for (int j = 0; j < 8; ++j)
                u.s[j] = f2bf(ap[(size_t)(kk * 32 + hi * 8 + j) * HW]);
            bfr[kk] = u.v;
        }

        f32x4 acc[9];
#pragma unroll
        for (int m = 0; m < 9; ++m) acc[m] = (f32x4){0.f, 0.f, 0.f, 0.f};

#pragma unroll
        for (int kk = 0; kk < 4; ++kk) {
            const int k0 = kk * 32 + hi * 8;
#pragma unroll
            for (int m = 0; m < 9; ++m) {
                bf16x8 af = *(const bf16x8*)(&Asm[(m * 16 + li) * APAD + k0]);
                acc[m] = __builtin_amdgcn_mfma_f32_16x16x32_bf16(af, bfr[kk], acc[m], 0, 0, 0);
            }
        }

        // epilogue: D row = c_out, col = px; two 256B runs per store instr
        const size_t pxoff = (size_t)b * HW + px;
#pragma unroll
        for (int m = 0; m < 8; ++m) {
            int c0 = m * 16 + rbase;
            ushort4 pk;
            pk.x = f2bf(acc[m].x + vr[m][0]);
            pk.y = f2bf(acc[m].y + vr[m][1]);
            pk.z = f2bf(acc[m].z + vr[m][2]);
            pk.w = f2bf(acc[m].w + vr[m][3]);
            *(ushort4*)(y2 + ((size_t)(c0 >> 3) * NPIX + pxoff) * 8 + (c0 & 7)) = pk;
        }
        if (rbase == 0) {  // row 128 = v.a2
            z2[pxoff] = acc[8].x + sv;
        }
    }
}

// ---------------- K3: MFMA correlation, barrier-free main loop -------------
// D[i][j] = sum_c x1bf[h][u8+i][c] * y2[h+di-4][u8+j-4][c]; band j-i in [0,8]
__global__ __launch_bounds__(256, 4) void k3_corr(
    const float* __restrict__ x1, const unsigned short* __restrict__ y2,
    const float* __restrict__ z2, float* __restrict__ out) {
    __shared__ float Zs[9 * 104];        // 3744 B
    __shared__ float Es[81 * ESW];       // 32400 B

    const int t = threadIdx.x;
    const int bx = blockIdx.x;                 // 0..95
    const int b = blockIdx.y;
    const int h = (bx & 7) * 12 + (bx >> 3);   // XCD-chunked row swizzle (bijective)

    const int wv = t >> 6;       // wave 0..3
    const int l = t & 63;
    const int li = l & 15;       // fragment row/col selector
    const int hi = l >> 4;       // k-seg selector 0..3

    // stage z-term halo
    for (int cell = t; cell < 936; cell += 256) {
        int r = cell / 104, sx = cell - r * 104;
        int hs = h - 4 + r, wsx = sx - 4;
        float zv = 0.f;
        if ((unsigned)hs < 96u && (unsigned)wsx < 96u)
            zv = z2[(size_t)b * HW + hs * 96 + wsx];
        Zs[cell] = zv;
    }

    // A-frags direct from raw f32 input1 (once per block)
    bf16x8 afr[3][4];
    const float* x1b = x1 + (size_t)b * (CIN * HW) + (size_t)h * 96;
#pragma unroll
    for (int g = 0; g < 3; ++g) {
        const int px = (wv * 3 + g) * 8 + li;
#pragma unroll
        for (int cc = 0; cc < 4; ++cc) {
            union { bf16x8 v; unsigned short s[8]; } u;
            if (px < 96) {
#pragma unroll
                for (int j = 0; j < 8; ++j)
                    u.s[j] = f2bf(x1b[(size_t)(cc * 32 + hi * 8 + j) * HW + px]);
            } else {
#pragma unroll
                for (int j = 0; j < 8; ++j) u.s[j] = 0;
            }
            afr[g][cc] = u.v;
        }
    }
    __syncthreads();   // Zs ready

    for (int di = 0; di < 9; ++di) {
        const int hs = h - 4 + di;
        const bool rowok = ((unsigned)hs < 96u);
        const long rb = ((long)b * HW + (long)hs * 96) * 8;

        f32x4 ac[3];
#pragma unroll
        for (int g = 0; g < 3; ++g) ac[g] = (f32x4){0.f, 0.f, 0.f, 0.f};

#pragma unroll
        for (int cc = 0; cc < 4; ++cc) {
            const long sb = (long)(cc * 4 + hi) * NPIX * 8 + rb;
#pragma unroll
            for (int g = 0; g < 3; ++g) {
                const int pxj = (wv * 3 + g) * 8 + li - 4;
                uint4 v = make_uint4(0u, 0u, 0u, 0u);
                if (rowok && (unsigned)pxj < 96u)
                    v = *(const uint4*)(y2 + sb + (long)pxj * 8);
                union { uint4 u; bf16x8 f; } cv; cv.u = v;
                ac[g] = __builtin_amdgcn_mfma_f32_16x16x32_bf16(
                    afr[g][cc], cv.f, ac[g], 0, 0, 0);
            }
        }

        // band extract into Es (no barrier; each cell written exactly once)
        if (l < 32) {
#pragma unroll
            for (int g = 0; g < 3; ++g) {
                const int uu = wv * 3 + g;
                const float zv = Zs[di * 104 + uu * 8 + li];
#pragma unroll
                for (int reg = 0; reg < 4; ++reg) {
                    const int i = hi * 4 + reg;     // hi in {0,1} -> i 0..7
                    const int dji = li - i;
                    if (dji >= 0 && dji <= 8)
                        Es[(di * 9 + dji) * ESW + uu * 8 + i] =
                            (ac[g][reg] + zv) * SCALE;
                }
            }
        }
    }

    __syncthreads();
    // bulk coalesced store: 81 shift-planes x 96 w
    const size_t ob = (size_t)b * 81 * HW + (size_t)h * 96;
    for (int idx = t; idx < 81 * 96; idx += 256) {
        int s = idx / 96, w = idx - s * 96;
        out[ob + (size_t)s * HW + w] = Es[s * ESW + w];
    }
}

// ---------------- host ------------------------------------------------------
extern "C" void kernel_launch(void* const* d_in, const int* in_sizes, int n_in,
                              void* d_out, int out_size, void* d_ws, size_t ws_size,
                              hipStream_t stream) {
    const float* input1 = (const float*)d_in[0];
    const float* input2 = (const float*)d_in[1];
    const float* proj_w = (const float*)d_in[2];
    const float* proj_b = (const float*)d_in[3];
    float* out = (float*)d_out;

    char* ws = (char*)d_ws;
    const size_t AB_OFF = 0;                      // 144*128*2 = 36864
    const size_t V_OFF  = 36864;                  // 512
    const size_t S_OFF  = 37376;                  // 4
    const size_t Y2_OFF = 40960;                  // 294912*128*2 = 75497472
    const size_t Z2_OFF = Y2_OFF + 75497472ull;   // 294912*4 = 1179648
    const size_t NEED   = Z2_OFF + 1179648ull;
    if (ws_size < NEED) return;  // fail loudly (output stays poisoned)

    unsigned short* Abuf = (unsigned short*)(ws + AB_OFF);
    float* vbuf = (float*)(ws + V_OFF);
    float* sbuf = (float*)(ws + S_OFF);
    unsigned short* y2 = (unsigned short*)(ws + Y2_OFF);
    float* z2 = (float*)(ws + Z2_OFF);

    k1_prep<<<dim3(144), dim3(128), 0, stream>>>(proj_w, proj_b, Abuf, vbuf, sbuf);
    k2_proj<<<dim3(4608 / NT), dim3(256), 0, stream>>>(input2, Abuf, vbuf, sbuf, y2, z2);
    k3_corr<<<dim3(96, 32), dim3(256), 0, stream>>>(input1, y2, z2, out);
}

// Round 5
// 206.256 us; speedup vs baseline: 1.9277x; 1.9277x over previous
//
#include <hip/hip_runtime.h>
#include <stdint.h>

#define B_   32
#define CIN  128
#define HH   96
#define WW   96
#define HW   (HH*WW)        // 9216
#define NPIX (B_*HW)        // 294912
#define AROWS 144
#define APAD  136           // bf16 elems per Asm row (272 B)
#define SCALE 0.08838834764831845f  // 1/sqrt(128)
#define ESW   100           // epilogue tile row stride (bank-spread)

typedef __attribute__((ext_vector_type(8))) short bf16x8;
typedef __attribute__((ext_vector_type(4))) float f32x4;

__device__ inline unsigned short f2bf(float f) {
    unsigned int u = __float_as_uint(f);
    u += 0x7fffu + ((u >> 16) & 1u);   // round-to-nearest-even
    return (unsigned short)(u >> 16);
}

// in-row XOR swizzle for 128B-aligned rows of 64 bf16: bijective (bits 4-6)
__device__ inline int bswz(int row, int byteoff) {
    return row * 128 + (byteoff ^ (((row ^ (row >> 3)) & 7) << 4));
}

// ---------------- K1: Abuf[144][128] = [W^T W ; v ; 0], vbuf, sbuf ----------
__global__ __launch_bounds__(128) void k1_prep(
    const float* __restrict__ Wm, const float* __restrict__ bias,
    unsigned short* __restrict__ Abuf, float* __restrict__ vbuf,
    float* __restrict__ sbuf) {
    int r = blockIdx.x;      // 0..143
    int c = threadIdx.x;     // 0..127
    float acc = 0.f;
    if (r < 128) {
        for (int f = 0; f < 128; ++f)
            acc += Wm[f * 128 + r] * Wm[f * 128 + c];
    } else if (r == 128) {
        for (int f = 0; f < 128; ++f)
            acc += Wm[f * 128 + c] * bias[f];
        vbuf[c] = acc;
        if (c == 0) {
            float s = 0.f;
            for (int f = 0; f < 128; ++f) s += bias[f] * bias[f];
            sbuf[0] = s;
        }
    }
    Abuf[r * 128 + c] = f2bf(acc);
}

// ---- K2: y2[seg][b][hw][8ch] = (M a2 + v) bf16 planar; z2 = v.a2 + s ------
// 512 thr, 128-px tile, single barrier. B staged via float4 + swizzled LDS.
__global__ __launch_bounds__(512, 4) void k2_proj(
    const float* __restrict__ a2, const unsigned short* __restrict__ Abuf,
    const float* __restrict__ vbuf, const float* __restrict__ sbuf,
    unsigned short* __restrict__ y2, float* __restrict__ z2) {
    __shared__ __align__(16) unsigned short Asm[AROWS * APAD];   // 39168 B
    __shared__ __align__(128) unsigned char Bsm[2][128 * 128];   // 32768 B

    const int t = threadIdx.x;
    const int tile = blockIdx.x;          // 0..2303
    const int b = tile / 72;
    const int hw0 = (tile - b * 72) * 128;

    // stage A once (144 rows x 128 bf16 = 2304 x 16B)
    for (int i = t; i < 2304; i += 512) {
        int row = i >> 4, seg = i & 15;
        *(uint4*)(&Asm[row * APAD + seg * 8]) =
            *(const uint4*)(Abuf + row * 128 + seg * 8);
    }

    // stage B: 128 px x 128 ch; float4 reads, paired-channel b32 swizzled writes
    {
        const int pxq = t & 31;           // px quad 0..31
        const int ctp = t >> 5;           // ch-pair 0..15
        const float* a2b = a2 + (size_t)b * (CIN * HW) + hw0 + pxq * 4;
#pragma unroll
        for (int it = 0; it < 4; ++it) {
            const int cc0 = (ctp + it * 16) * 2;      // even channel
            float4 f0 = *(const float4*)(a2b + (size_t)cc0 * HW);
            float4 f1 = *(const float4*)(a2b + (size_t)(cc0 + 1) * HW);
            unsigned char* pl = Bsm[cc0 >> 6];
            const int bo = (cc0 & 63) * 2;
            float a0[4] = {f0.x, f0.y, f0.z, f0.w};
            float a1[4] = {f1.x, f1.y, f1.z, f1.w};
#pragma unroll
            for (int r = 0; r < 4; ++r) {
                unsigned int pk = (unsigned int)f2bf(a0[r]) |
                                  ((unsigned int)f2bf(a1[r]) << 16);
                *(unsigned int*)(&pl[bswz(pxq * 4 + r, bo)]) = pk;
            }
        }
    }
    __syncthreads();

    const int wv = t >> 6;       // wave 0..7 -> px group
    const int l = t & 63;
    const int li = l & 15;
    const int hi = l >> 4;
    const int rbase = hi * 4;
    const int pxl = wv * 16 + li;     // 0..127 within tile

    // B-frags from swizzled LDS
    bf16x8 bfr[4];
#pragma unroll
    for (int kk = 0; kk < 4; ++kk) {
        const int k0 = kk * 32 + hi * 8;
        bfr[kk] = *(const bf16x8*)(&Bsm[k0 >> 6][bswz(pxl, (k0 & 63) * 2)]);
    }

    f32x4 acc[9];
#pragma unroll
    for (int m = 0; m < 9; ++m) acc[m] = (f32x4){0.f, 0.f, 0.f, 0.f};

#pragma unroll
    for (int kk = 0; kk < 4; ++kk) {
        const int k0 = kk * 32 + hi * 8;
#pragma unroll
        for (int m = 0; m < 9; ++m) {
            bf16x8 af = *(const bf16x8*)(&Asm[(m * 16 + li) * APAD + k0]);
            acc[m] = __builtin_amdgcn_mfma_f32_16x16x32_bf16(af, bfr[kk], acc[m], 0, 0, 0);
        }
    }

    // epilogue: paired hi-halves complete 256B runs per instr (proven clean)
    const int px = hw0 + pxl;
    const size_t pxoff = (size_t)b * HW + px;
#pragma unroll
    for (int m = 0; m < 8; ++m) {
        int c0 = m * 16 + rbase;
        ushort4 pk;
        pk.x = f2bf(acc[m].x + vbuf[c0 + 0]);
        pk.y = f2bf(acc[m].y + vbuf[c0 + 1]);
        pk.z = f2bf(acc[m].z + vbuf[c0 + 2]);
        pk.w = f2bf(acc[m].w + vbuf[c0 + 3]);
        *(ushort4*)(y2 + ((size_t)(c0 >> 3) * NPIX + pxoff) * 8 + (c0 & 7)) = pk;
    }
    if (rbase == 0) {  // row 128 = v.a2
        z2[pxoff] = acc[8].x + sbuf[0];
    }
}

// ---------------- K3: MFMA correlation, barrier-free main loop -------------
// D[i][j] = sum_c x1bf[h][u8+i][c] * y2[h+di-4][u8+j-4][c]; band j-i in [0,8]
__global__ __launch_bounds__(256, 4) void k3_corr(
    const float* __restrict__ x1, const unsigned short* __restrict__ y2,
    const float* __restrict__ z2, float* __restrict__ out) {
    __shared__ float Zs[9 * 104];                          // 3744 B
    __shared__ __align__(128) unsigned char EX[32512];     // Es (32400) / Xs (26624)
    float* Es = (float*)EX;
    // Xs: [2][104 rows][64 bf16], rows 96..103 zero

    const int t = threadIdx.x;
    const int bx = blockIdx.x;                 // 0..95
    const int b = blockIdx.y;
    const int h = (bx & 7) * 12 + (bx >> 3);   // XCD-chunked row swizzle (bijective)

    const int wv = t >> 6;       // wave 0..3
    const int l = t & 63;
    const int li = l & 15;
    const int hi = l >> 4;

    // stage z-term halo
    for (int cell = t; cell < 936; cell += 256) {
        int r = cell / 104, sx = cell - r * 104;
        int hs = h - 4 + r, wsx = sx - 4;
        float zv = 0.f;
        if ((unsigned)hs < 96u && (unsigned)wsx < 96u)
            zv = z2[(size_t)b * HW + hs * 96 + wsx];
        Zs[cell] = zv;
    }

    // zero pad rows 96..103 of both Xs planes (2 planes x 8 rows x 128 B)
    {
        unsigned char* x0 = EX;
        if (t < 128) {
            int pl = t >> 6, r = (t >> 3) & 7, sgm = t & 7;
            *(uint4*)(&x0[pl * 13312 + (96 + r) * 128 + sgm * 16]) =
                make_uint4(0u, 0u, 0u, 0u);
        }
    }
    // stage Xs: x1 row-block [128 ch][96 px] -> swizzled [2][104][64] bf16
    {
        const float* x1b = x1 + (size_t)b * (CIN * HW) + (size_t)h * 96;
#pragma unroll
        for (int it = 0; it < 6; ++it) {
            int idx = t + it * 256;           // 0..1535
            int ccp = idx / 24;               // 0..63
            int pxq = idx - ccp * 24;         // 0..23
            int cc0 = ccp * 2;
            float4 f0 = *(const float4*)(x1b + (size_t)cc0 * HW + pxq * 4);
            float4 f1 = *(const float4*)(x1b + (size_t)(cc0 + 1) * HW + pxq * 4);
            unsigned char* pl = EX + (cc0 >> 6) * 13312;
            const int bo = (cc0 & 63) * 2;
            float a0[4] = {f0.x, f0.y, f0.z, f0.w};
            float a1[4] = {f1.x, f1.y, f1.z, f1.w};
#pragma unroll
            for (int r = 0; r < 4; ++r) {
                unsigned int pk = (unsigned int)f2bf(a0[r]) |
                                  ((unsigned int)f2bf(a1[r]) << 16);
                *(unsigned int*)(&pl[bswz(pxq * 4 + r, bo)]) = pk;
            }
        }
    }
    __syncthreads();

    // A-frags from swizzled Xs (12 b128 reads)
    bf16x8 afr[3][4];
#pragma unroll
    for (int g = 0; g < 3; ++g) {
        const int px = (wv * 3 + g) * 8 + li;     // 0..103 (pad rows zero)
#pragma unroll
        for (int cc = 0; cc < 4; ++cc) {
            const int k0 = cc * 32 + hi * 8;
            afr[g][cc] = *(const bf16x8*)(
                &EX[(k0 >> 6) * 13312 + bswz(px, (k0 & 63) * 2)]);
        }
    }
    __syncthreads();   // all Xs reads done before Es writes

    for (int di = 0; di < 9; ++di) {
        const int hs = h - 4 + di;
        const bool rowok = ((unsigned)hs < 96u);
        const long rb = ((long)b * HW + (long)hs * 96) * 8;

        f32x4 ac[3];
#pragma unroll
        for (int g = 0; g < 3; ++g) ac[g] = (f32x4){0.f, 0.f, 0.f, 0.f};

#pragma unroll
        for (int cc = 0; cc < 4; ++cc) {
            const long sb = (long)(cc * 4 + hi) * NPIX * 8 + rb;
#pragma unroll
            for (int g = 0; g < 3; ++g) {
                const int pxj = (wv * 3 + g) * 8 + li - 4;
                uint4 v = make_uint4(0u, 0u, 0u, 0u);
                if (rowok && (unsigned)pxj < 96u)
                    v = *(const uint4*)(y2 + sb + (long)pxj * 8);
                union { uint4 u; bf16x8 f; } cv; cv.u = v;
                ac[g] = __builtin_amdgcn_mfma_f32_16x16x32_bf16(
                    afr[g][cc], cv.f, ac[g], 0, 0, 0);
            }
        }

        // band extract into Es (each cell written exactly once)
        if (l < 32) {
#pragma unroll
            for (int g = 0; g < 3; ++g) {
                const int uu = wv * 3 + g;
                const float zv = Zs[di * 104 + uu * 8 + li];
#pragma unroll
                for (int reg = 0; reg < 4; ++reg) {
                    const int i = hi * 4 + reg;     // hi in {0,1} -> i 0..7
                    const int dji = li - i;
                    if (dji >= 0 && dji <= 8)
                        Es[(di * 9 + dji) * ESW + uu * 8 + i] =
                            (ac[g][reg] + zv) * SCALE;
                }
            }
        }
    }

    __syncthreads();
    // bulk coalesced store: 81 shift-planes x 96 w
    const size_t ob = (size_t)b * 81 * HW + (size_t)h * 96;
    for (int idx = t; idx < 81 * 96; idx += 256) {
        int s = idx / 96, w = idx - s * 96;
        out[ob + (size_t)s * HW + w] = Es[s * ESW + w];
    }
}

// ---------------- host ------------------------------------------------------
extern "C" void kernel_launch(void* const* d_in, const int* in_sizes, int n_in,
                              void* d_out, int out_size, void* d_ws, size_t ws_size,
                              hipStream_t stream) {
    const float* input1 = (const float*)d_in[0];
    const float* input2 = (const float*)d_in[1];
    const float* proj_w = (const float*)d_in[2];
    const float* proj_b = (const float*)d_in[3];
    float* out = (float*)d_out;

    char* ws = (char*)d_ws;
    const size_t AB_OFF = 0;                      // 144*128*2 = 36864
    const size_t V_OFF  = 36864;                  // 512
    const size_t S_OFF  = 37376;                  // 4
    const size_t Y2_OFF = 40960;                  // 294912*128*2 = 75497472
    const size_t Z2_OFF = Y2_OFF + 75497472ull;   // 294912*4 = 1179648
    const size_t NEED   = Z2_OFF + 1179648ull;
    if (ws_size < NEED) return;  // fail loudly (output stays poisoned)

    unsigned short* Abuf = (unsigned short*)(ws + AB_OFF);
    float* vbuf = (float*)(ws + V_OFF);
    float* sbuf = (float*)(ws + S_OFF);
    unsigned short* y2 = (unsigned short*)(ws + Y2_OFF);
    float* z2 = (float*)(ws + Z2_OFF);

    k1_prep<<<dim3(144), dim3(128), 0, stream>>>(proj_w, proj_b, Abuf, vbuf, sbuf);
    k2_proj<<<dim3(2304), dim3(512), 0, stream>>>(input2, Abuf, vbuf, sbuf, y2, z2);
    k3_corr<<<dim3(96, 32), dim3(256), 0, stream>>>(input1, y2, z2, out);
}

// Round 6
// 183.442 us; speedup vs baseline: 2.1674x; 1.1244x over previous
//
#include <hip/hip_runtime.h>
#include <stdint.h>

#define B_   32
#define CIN  128
#define HH   96
#define WW   96
#define HW   (HH*WW)        // 9216
#define NPIX (B_*HW)        // 294912
#define AROWS 144
#define APAD  136           // bf16 elems per Asm row (272 B)
#define SCALE 0.08838834764831845f  // 1/sqrt(128)
#define ESW   100           // epilogue tile row stride (bank-spread)

// ws layout (bytes)
#define AB_OFF 0u
#define V_OFF  36864u
#define S_OFF  37376u
#define Y2_OFF 40960u
#define Z2_OFF (Y2_OFF + 75497472u)
#define ZP_OFF (Z2_OFF + 1179648u)          // 16 KB zero page
#define WS_NEED (ZP_OFF + 16384u)

typedef __attribute__((ext_vector_type(8))) short bf16x8;
typedef __attribute__((ext_vector_type(4))) float f32x4;

__device__ inline unsigned short f2bf(float f) {
    unsigned int u = __float_as_uint(f);
    u += 0x7fffu + ((u >> 16) & 1u);   // round-to-nearest-even
    return (unsigned short)(u >> 16);
}

// in-row XOR swizzle for 128B-aligned rows of 64 bf16: bijective (bits 4-6)
__device__ inline int bswz(int row, int byteoff) {
    return row * 128 + (byteoff ^ (((row ^ (row >> 3)) & 7) << 4));
}

// ---------------- K1: Abuf = [W^T W ; v ; 0], vbuf, sbuf, zero-page --------
__global__ __launch_bounds__(128) void k1_prep(
    const float* __restrict__ Wm, const float* __restrict__ bias,
    unsigned short* __restrict__ Abuf, float* __restrict__ vbuf,
    float* __restrict__ sbuf, char* __restrict__ zp) {
    int r = blockIdx.x;      // 0..143
    int c = threadIdx.x;     // 0..127
    // zero the 16KB zero page (K3 OOB-lane load target)
    int gid = r * 128 + c;
    if (gid < 1024)
        *(uint4*)(zp + gid * 16) = make_uint4(0u, 0u, 0u, 0u);

    float acc = 0.f;
    if (r < 128) {
        for (int f = 0; f < 128; ++f)
            acc += Wm[f * 128 + r] * Wm[f * 128 + c];
    } else if (r == 128) {
        for (int f = 0; f < 128; ++f)
            acc += Wm[f * 128 + c] * bias[f];
        vbuf[c] = acc;
        if (c == 0) {
            float s = 0.f;
            for (int f = 0; f < 128; ++f) s += bias[f] * bias[f];
            sbuf[0] = s;
        }
    }
    Abuf[r * 128 + c] = f2bf(acc);
}

// ---- K2: y2[seg][b][hw][8ch] = (M a2 + v) bf16 planar; z2 = v.a2 + s ------
// 512 thr, 128-px tile, single barrier. B staged via float4 + swizzled LDS.
__global__ __launch_bounds__(512, 4) void k2_proj(
    const float* __restrict__ a2, const unsigned short* __restrict__ Abuf,
    const float* __restrict__ vbuf, const float* __restrict__ sbuf,
    unsigned short* __restrict__ y2, float* __restrict__ z2) {
    __shared__ __align__(16) unsigned short Asm[AROWS * APAD];   // 39168 B
    __shared__ __align__(128) unsigned char Bsm[2][128 * 128];   // 32768 B

    const int t = threadIdx.x;
    const int tile = blockIdx.x;          // 0..2303
    const int b = tile / 72;
    const int hw0 = (tile - b * 72) * 128;

    // stage A once (144 rows x 128 bf16 = 2304 x 16B)
    for (int i = t; i < 2304; i += 512) {
        int row = i >> 4, seg = i & 15;
        *(uint4*)(&Asm[row * APAD + seg * 8]) =
            *(const uint4*)(Abuf + row * 128 + seg * 8);
    }

    // stage B: 128 px x 128 ch; float4 reads, paired-channel b32 swizzled writes
    {
        const int pxq = t & 31;           // px quad 0..31
        const int ctp = t >> 5;           // ch-pair 0..15
        const float* a2b = a2 + (size_t)b * (CIN * HW) + hw0 + pxq * 4;
#pragma unroll
        for (int it = 0; it < 4; ++it) {
            const int cc0 = (ctp + it * 16) * 2;      // even channel
            float4 f0 = *(const float4*)(a2b + (size_t)cc0 * HW);
            float4 f1 = *(const float4*)(a2b + (size_t)(cc0 + 1) * HW);
            unsigned char* pl = Bsm[cc0 >> 6];
            const int bo = (cc0 & 63) * 2;
            float a0[4] = {f0.x, f0.y, f0.z, f0.w};
            float a1[4] = {f1.x, f1.y, f1.z, f1.w};
#pragma unroll
            for (int r = 0; r < 4; ++r) {
                unsigned int pk = (unsigned int)f2bf(a0[r]) |
                                  ((unsigned int)f2bf(a1[r]) << 16);
                *(unsigned int*)(&pl[bswz(pxq * 4 + r, bo)]) = pk;
            }
        }
    }
    __syncthreads();

    const int wv = t >> 6;       // wave 0..7 -> px group
    const int l = t & 63;
    const int li = l & 15;
    const int hi = l >> 4;
    const int rbase = hi * 4;
    const int pxl = wv * 16 + li;     // 0..127 within tile

    // B-frags from swizzled LDS
    bf16x8 bfr[4];
#pragma unroll
    for (int kk = 0; kk < 4; ++kk) {
        const int k0 = kk * 32 + hi * 8;
        bfr[kk] = *(const bf16x8*)(&Bsm[k0 >> 6][bswz(pxl, (k0 & 63) * 2)]);
    }

    f32x4 acc[9];
#pragma unroll
    for (int m = 0; m < 9; ++m) acc[m] = (f32x4){0.f, 0.f, 0.f, 0.f};

#pragma unroll
    for (int kk = 0; kk < 4; ++kk) {
        const int k0 = kk * 32 + hi * 8;
#pragma unroll
        for (int m = 0; m < 9; ++m) {
            bf16x8 af = *(const bf16x8*)(&Asm[(m * 16 + li) * APAD + k0]);
            acc[m] = __builtin_amdgcn_mfma_f32_16x16x32_bf16(af, bfr[kk], acc[m], 0, 0, 0);
        }
    }

    // epilogue: paired hi-halves complete 256B runs per instr
    const int px = hw0 + pxl;
    const size_t pxoff = (size_t)b * HW + px;
#pragma unroll
    for (int m = 0; m < 8; ++m) {
        int c0 = m * 16 + rbase;
        ushort4 pk;
        pk.x = f2bf(acc[m].x + vbuf[c0 + 0]);
        pk.y = f2bf(acc[m].y + vbuf[c0 + 1]);
        pk.z = f2bf(acc[m].z + vbuf[c0 + 2]);
        pk.w = f2bf(acc[m].w + vbuf[c0 + 3]);
        *(ushort4*)(y2 + ((size_t)(c0 >> 3) * NPIX + pxoff) * 8 + (c0 & 7)) = pk;
    }
    if (rbase == 0) {  // row 128 = v.a2
        z2[pxoff] = acc[8].x + sbuf[0];
    }
}

// ---------------- K3: MFMA correlation, software-pipelined over di ---------
// D[i][j] = sum_c x1bf[h][u8+i][c] * y2[h+di-4][u8+j-4][c]; band j-i in [0,8]
__global__ __launch_bounds__(256, 3) void k3_corr(
    const float* __restrict__ x1, const char* __restrict__ wsb,
    const float* __restrict__ z2, float* __restrict__ out) {
    __shared__ float Zs[9 * 104];                          // 3744 B
    __shared__ __align__(128) unsigned char EX[32512];     // Es (32400) / Xs (26624)
    float* Es = (float*)EX;
    // Xs: [2][104 rows][64 bf16], rows 96..103 zero

    const int t = threadIdx.x;
    const int bx = blockIdx.x;                 // 0..95
    const int b = blockIdx.y;
    const int h = (bx & 7) * 12 + (bx >> 3);   // XCD-chunked row swizzle (bijective)

    const int wv = t >> 6;       // wave 0..3
    const int l = t & 63;
    const int li = l & 15;
    const int hi = l >> 4;

    // stage z-term halo
    for (int cell = t; cell < 936; cell += 256) {
        int r = cell / 104, sx = cell - r * 104;
        int hs = h - 4 + r, wsx = sx - 4;
        float zv = 0.f;
        if ((unsigned)hs < 96u && (unsigned)wsx < 96u)
            zv = z2[(size_t)b * HW + hs * 96 + wsx];
        Zs[cell] = zv;
    }

    // zero pad rows 96..103 of both Xs planes
    if (t < 128) {
        int pl = t >> 6, r = (t >> 3) & 7, sgm = t & 7;
        *(uint4*)(&EX[pl * 13312 + (96 + r) * 128 + sgm * 16]) =
            make_uint4(0u, 0u, 0u, 0u);
    }
    // stage Xs: x1 row-block [128 ch][96 px] -> swizzled [2][104][64] bf16
    {
        const float* x1b = x1 + (size_t)b * (CIN * HW) + (size_t)h * 96;
#pragma unroll
        for (int it = 0; it < 6; ++it) {
            int idx = t + it * 256;           // 0..1535
            int ccp = idx / 24;               // 0..63
            int pxq = idx - ccp * 24;         // 0..23
            int cc0 = ccp * 2;
            float4 f0 = *(const float4*)(x1b + (size_t)cc0 * HW + pxq * 4);
            float4 f1 = *(const float4*)(x1b + (size_t)(cc0 + 1) * HW + pxq * 4);
            unsigned char* pl = EX + (cc0 >> 6) * 13312;
            const int bo = (cc0 & 63) * 2;
            float a0[4] = {f0.x, f0.y, f0.z, f0.w};
            float a1[4] = {f1.x, f1.y, f1.z, f1.w};
#pragma unroll
            for (int r = 0; r < 4; ++r) {
                unsigned int pk = (unsigned int)f2bf(a0[r]) |
                                  ((unsigned int)f2bf(a1[r]) << 16);
                *(unsigned int*)(&pl[bswz(pxq * 4 + r, bo)]) = pk;
            }
        }
    }

    // per-lane 32-bit ws-offsets for B-loads; OOB px -> zero page
    unsigned offb[12];
#pragma unroll
    for (int cc = 0; cc < 4; ++cc)
#pragma unroll
        for (int g = 0; g < 3; ++g) {
            const int pxj = (wv * 3 + g) * 8 + li - 4;
            long off;
            if ((unsigned)pxj < 96u)
                off = (long)Y2_OFF +
                      ((long)(cc * 4 + hi) * NPIX + (long)b * HW +
                       (long)(h - 4) * 96 + pxj) * 16;
            else
                off = (long)ZP_OFF;
            offb[cc * 3 + g] = (unsigned)off;
        }

    __syncthreads();

    // A-frags from swizzled Xs (12 b128 reads), held in registers
    bf16x8 afr[3][4];
#pragma unroll
    for (int g = 0; g < 3; ++g) {
        const int px = (wv * 3 + g) * 8 + li;     // 0..103 (pad rows zero)
#pragma unroll
        for (int cc = 0; cc < 4; ++cc) {
            const int k0 = cc * 32 + hi * 8;
            afr[g][cc] = *(const bf16x8*)(
                &EX[(k0 >> 6) * 13312 + bswz(px, (k0 & 63) * 2)]);
        }
    }
    __syncthreads();   // all Xs reads done before Es writes

    // software pipeline: row di+1 prefetched (6 early / 6 late) during row di
    uint4 pvA[2][6], pvB[2][6];
#pragma unroll
    for (int q = 0; q < 6; ++q)
        pvA[0][q] = *(const uint4*)(wsb + offb[q]);
#pragma unroll
    for (int q = 0; q < 6; ++q)
        pvB[0][q] = *(const uint4*)(wsb + offb[6 + q]);

#pragma unroll
    for (int di = 0; di < 9; ++di) {
        const int cur = di & 1, nxt = cur ^ 1;
        // early prefetch: next row cc0,1
        if (di < 8) {
#pragma unroll
            for (int q = 0; q < 6; ++q)
                pvA[nxt][q] = *(const uint4*)(wsb + offb[q] + (di + 1) * 1536);
        }

        const int hs = h - 4 + di;
        f32x4 ac[3];
#pragma unroll
        for (int g = 0; g < 3; ++g) ac[g] = (f32x4){0.f, 0.f, 0.f, 0.f};

        if ((unsigned)hs < 96u) {     // wave-uniform: skip MFMA for pad rows
#pragma unroll
            for (int cc = 0; cc < 4; ++cc)
#pragma unroll
                for (int g = 0; g < 3; ++g) {
                    union { uint4 u; bf16x8 f; } cv;
                    cv.u = (cc < 2) ? pvA[cur][cc * 3 + g]
                                    : pvB[cur][(cc - 2) * 3 + g];
                    ac[g] = __builtin_amdgcn_mfma_f32_16x16x32_bf16(
                        afr[g][cc], cv.f, ac[g], 0, 0, 0);
                }
        }

        // band extract into Es (each cell written exactly once)
        if (l < 32) {
#pragma unroll
            for (int g = 0; g < 3; ++g) {
                const int uu = wv * 3 + g;
                const float zv = Zs[di * 104 + uu * 8 + li];
#pragma unroll
                for (int reg = 0; reg < 4; ++reg) {
                    const int i = hi * 4 + reg;     // hi in {0,1} -> i 0..7
                    const int dji = li - i;
                    if (dji >= 0 && dji <= 8)
                        Es[(di * 9 + dji) * ESW + uu * 8 + i] =
                            (ac[g][reg] + zv) * SCALE;
                }
            }
        }

        // late prefetch: next row cc2,3
        if (di < 8) {
#pragma unroll
            for (int q = 0; q < 6; ++q)
                pvB[nxt][q] = *(const uint4*)(wsb + offb[6 + q] + (di + 1) * 1536);
        }
    }

    __syncthreads();
    // bulk coalesced store: 81 shift-planes x 96 w
    const size_t ob = (size_t)b * 81 * HW + (size_t)h * 96;
    for (int idx = t; idx < 81 * 96; idx += 256) {
        int s = idx / 96, w = idx - s * 96;
        out[ob + (size_t)s * HW + w] = Es[s * ESW + w];
    }
}

// ---------------- host ------------------------------------------------------
extern "C" void kernel_launch(void* const* d_in, const int* in_sizes, int n_in,
                              void* d_out, int out_size, void* d_ws, size_t ws_size,
                              hipStream_t stream) {
    const float* input1 = (const float*)d_in[0];
    const float* input2 = (const float*)d_in[1];
    const float* proj_w = (const float*)d_in[2];
    const float* proj_b = (const float*)d_in[3];
    float* out = (float*)d_out;

    char* ws = (char*)d_ws;
    if (ws_size < WS_NEED) return;  // fail loudly (output stays poisoned)

    unsigned short* Abuf = (unsigned short*)(ws + AB_OFF);
    float* vbuf = (float*)(ws + V_OFF);
    float* sbuf = (float*)(ws + S_OFF);
    unsigned short* y2 = (unsigned short*)(ws + Y2_OFF);
    float* z2 = (float*)(ws + Z2_OFF);
    char* zp = ws + ZP_OFF;

    k1_prep<<<dim3(144), dim3(128), 0, stream>>>(proj_w, proj_b, Abuf, vbuf, sbuf, zp);
    k2_proj<<<dim3(2304), dim3(512), 0, stream>>>(input2, Abuf, vbuf, sbuf, y2, z2);
    k3_corr<<<dim3(96, 32), dim3(256), 0, stream>>>(input1, ws, z2, out);
}

// Round 7
// 169.472 us; speedup vs baseline: 2.3461x; 1.0824x over previous
//
#include <hip/hip_runtime.h>
#include <stdint.h>

#define B_   32
#define CIN  128
#define HH   96
#define WW   96
#define HW   (HH*WW)        // 9216
#define NPIX (B_*HW)        // 294912
#define AROWS 144
#define APAD  136           // bf16 elems per Asm row (272 B)
#define SCALE 0.08838834764831845f  // 1/sqrt(128)
#define ESW   97            // epilogue tile row stride (97 odd -> bank spread)

// ws layout (bytes)
#define AB_OFF 0u
#define V_OFF  36864u
#define S_OFF  37376u
#define Y2_OFF 40960u
#define Z2_OFF (Y2_OFF + 75497472u)
#define ZP_OFF (Z2_OFF + 1179648u)          // 16 KB zero page
#define WS_NEED (ZP_OFF + 16384u)

typedef __attribute__((ext_vector_type(8))) short bf16x8;
typedef __attribute__((ext_vector_type(4))) float f32x4;

__device__ inline unsigned short f2bf(float f) {
    unsigned int u = __float_as_uint(f);
    u += 0x7fffu + ((u >> 16) & 1u);   // round-to-nearest-even
    return (unsigned short)(u >> 16);
}

// in-row XOR swizzle for 128B-aligned rows of 64 bf16: bijective (bits 4-6)
__device__ inline int bswz(int row, int byteoff) {
    return row * 128 + (byteoff ^ (((row ^ (row >> 3)) & 7) << 4));
}

// ---------------- K1: Abuf = [W^T W ; v ; 0], vbuf, sbuf, zero-page --------
__global__ __launch_bounds__(128) void k1_prep(
    const float* __restrict__ Wm, const float* __restrict__ bias,
    unsigned short* __restrict__ Abuf, float* __restrict__ vbuf,
    float* __restrict__ sbuf, char* __restrict__ zp) {
    int r = blockIdx.x;      // 0..143
    int c = threadIdx.x;     // 0..127
    int gid = r * 128 + c;
    if (gid < 1024)
        *(uint4*)(zp + gid * 16) = make_uint4(0u, 0u, 0u, 0u);

    float acc = 0.f;
    if (r < 128) {
        for (int f = 0; f < 128; ++f)
            acc += Wm[f * 128 + r] * Wm[f * 128 + c];
    } else if (r == 128) {
        for (int f = 0; f < 128; ++f)
            acc += Wm[f * 128 + c] * bias[f];
        vbuf[c] = acc;
        if (c == 0) {
            float s = 0.f;
            for (int f = 0; f < 128; ++f) s += bias[f] * bias[f];
            sbuf[0] = s;
        }
    }
    Abuf[r * 128 + c] = f2bf(acc);
}

// ---- K2: y2[seg][b][hw][8ch] = (M a2 + v) bf16 planar; z2 = v.a2 + s ------
__global__ __launch_bounds__(512, 4) void k2_proj(
    const float* __restrict__ a2, const unsigned short* __restrict__ Abuf,
    const float* __restrict__ vbuf, const float* __restrict__ sbuf,
    unsigned short* __restrict__ y2, float* __restrict__ z2) {
    __shared__ __align__(16) unsigned short Asm[AROWS * APAD];   // 39168 B
    __shared__ __align__(128) unsigned char Bsm[2][128 * 128];   // 32768 B

    const int t = threadIdx.x;
    const int tile = blockIdx.x;          // 0..2303
    const int b = tile / 72;
    const int hw0 = (tile - b * 72) * 128;

    for (int i = t; i < 2304; i += 512) {
        int row = i >> 4, seg = i & 15;
        *(uint4*)(&Asm[row * APAD + seg * 8]) =
            *(const uint4*)(Abuf + row * 128 + seg * 8);
    }

    {
        const int pxq = t & 31;           // px quad 0..31
        const int ctp = t >> 5;           // ch-pair 0..15
        const float* a2b = a2 + (size_t)b * (CIN * HW) + hw0 + pxq * 4;
#pragma unroll
        for (int it = 0; it < 4; ++it) {
            const int cc0 = (ctp + it * 16) * 2;      // even channel
            float4 f0 = *(const float4*)(a2b + (size_t)cc0 * HW);
            float4 f1 = *(const float4*)(a2b + (size_t)(cc0 + 1) * HW);
            unsigned char* pl = Bsm[cc0 >> 6];
            const int bo = (cc0 & 63) * 2;
            float a0[4] = {f0.x, f0.y, f0.z, f0.w};
            float a1[4] = {f1.x, f1.y, f1.z, f1.w};
#pragma unroll
            for (int r = 0; r < 4; ++r) {
                unsigned int pk = (unsigned int)f2bf(a0[r]) |
                                  ((unsigned int)f2bf(a1[r]) << 16);
                *(unsigned int*)(&pl[bswz(pxq * 4 + r, bo)]) = pk;
            }
        }
    }
    __syncthreads();

    const int wv = t >> 6;
    const int l = t & 63;
    const int li = l & 15;
    const int hi = l >> 4;
    const int rbase = hi * 4;
    const int pxl = wv * 16 + li;

    bf16x8 bfr[4];
#pragma unroll
    for (int kk = 0; kk < 4; ++kk) {
        const int k0 = kk * 32 + hi * 8;
        bfr[kk] = *(const bf16x8*)(&Bsm[k0 >> 6][bswz(pxl, (k0 & 63) * 2)]);
    }

    f32x4 acc[9];
#pragma unroll
    for (int m = 0; m < 9; ++m) acc[m] = (f32x4){0.f, 0.f, 0.f, 0.f};

#pragma unroll
    for (int kk = 0; kk < 4; ++kk) {
        const int k0 = kk * 32 + hi * 8;
#pragma unroll
        for (int m = 0; m < 9; ++m) {
            bf16x8 af = *(const bf16x8*)(&Asm[(m * 16 + li) * APAD + k0]);
            acc[m] = __builtin_amdgcn_mfma_f32_16x16x32_bf16(af, bfr[kk], acc[m], 0, 0, 0);
        }
    }

    const int px = hw0 + pxl;
    const size_t pxoff = (size_t)b * HW + px;
#pragma unroll
    for (int m = 0; m < 8; ++m) {
        int c0 = m * 16 + rbase;
        ushort4 pk;
        pk.x = f2bf(acc[m].x + vbuf[c0 + 0]);
        pk.y = f2bf(acc[m].y + vbuf[c0 + 1]);
        pk.z = f2bf(acc[m].z + vbuf[c0 + 2]);
        pk.w = f2bf(acc[m].w + vbuf[c0 + 3]);
        *(ushort4*)(y2 + ((size_t)(c0 >> 3) * NPIX + pxoff) * 8 + (c0 & 7)) = pk;
    }
    if (rbase == 0) {
        z2[pxoff] = acc[8].x + sbuf[0];
    }
}

// -------- K3: MFMA correlation, 2 image rows packed per 16-row A-tile ------
// A rows 0-7 = row h px window, rows 8-15 = row h+1 same window.
// Round di (0..9): B row hs = h-4+di; plane0 shift-row di, plane1 shift-row di-1.
__global__ __launch_bounds__(256, 2) void k3_corr(
    const float* __restrict__ x1, const char* __restrict__ wsb,
    float* __restrict__ out) {
    // Xs phase: [2 im][2 chplane][96 rows][64 bf16] = 49152 B
    // Es phase: [2 im][81][ESW] f32 = 62856 B
    __shared__ __align__(128) unsigned char EX[62880];
    float* Es = (float*)EX;

    const int t = threadIdx.x;
    const int bx = blockIdx.x;                 // 0..47
    const int b = blockIdx.y;
    const int h = ((bx & 7) * 6 + (bx >> 3)) * 2;   // XCD-chunked, bijective

    const int wv = t >> 6;       // wave 0..3
    const int l = t & 63;
    const int li = l & 15;
    const int hi = l >> 4;

    // stage Xs: 2 image rows, [128 ch][96 px] f32 -> swizzled bf16 planes
    {
        const float* x1b = x1 + (size_t)b * (CIN * HW) + (size_t)h * 96;
#pragma unroll
        for (int im = 0; im < 2; ++im) {
            const float* xr = x1b + im * 96;
#pragma unroll
            for (int it = 0; it < 6; ++it) {
                int idx = t + it * 256;           // 0..1535
                int ccp = idx / 24;               // 0..63
                int pxq = idx - ccp * 24;         // 0..23
                int cc0 = ccp * 2;
                float4 f0 = *(const float4*)(xr + (size_t)cc0 * HW + pxq * 4);
                float4 f1 = *(const float4*)(xr + (size_t)(cc0 + 1) * HW + pxq * 4);
                unsigned char* pl = EX + im * 24576 + (cc0 >> 6) * 12288;
                const int bo = (cc0 & 63) * 2;
                float a0[4] = {f0.x, f0.y, f0.z, f0.w};
                float a1[4] = {f1.x, f1.y, f1.z, f1.w};
#pragma unroll
                for (int r = 0; r < 4; ++r) {
                    unsigned int pk = (unsigned int)f2bf(a0[r]) |
                                      ((unsigned int)f2bf(a1[r]) << 16);
                    *(unsigned int*)(&pl[bswz(pxq * 4 + r, bo)]) = pk;
                }
            }
        }
    }

    // per-lane ws-offsets for B-loads; OOB px -> zero page
    unsigned offb[12];
#pragma unroll
    for (int cc = 0; cc < 4; ++cc)
#pragma unroll
        for (int g = 0; g < 3; ++g) {
            const int pxj = (wv * 3 + g) * 8 + li - 4;
            long off;
            if ((unsigned)pxj < 96u)
                off = (long)Y2_OFF +
                      ((long)(cc * 4 + hi) * NPIX + (long)b * HW +
                       (long)(h - 4) * 96 + pxj) * 16;
            else
                off = (long)ZP_OFF;
            offb[cc * 3 + g] = (unsigned)off;
        }

    // per-lane z2 offsets (col part); row walks by +384B per round
    int offz[3];
#pragma unroll
    for (int g = 0; g < 3; ++g) {
        const int zc = (wv * 3 + g) * 8 + li - 4;
        offz[g] = ((unsigned)zc < 96u)
            ? (int)Z2_OFF + (b * HW + (h - 4) * 96 + zc) * 4
            : (int)ZP_OFF;
    }

    __syncthreads();

    // A-frags from swizzled Xs: row = li&7, image plane = li>>3
    bf16x8 afr[3][4];
    {
        const int imA = li >> 3;
        const int pA = li & 7;
#pragma unroll
        for (int g = 0; g < 3; ++g) {
            const int px = (wv * 3 + g) * 8 + pA;
#pragma unroll
            for (int cc = 0; cc < 4; ++cc) {
                const int k0 = cc * 32 + hi * 8;
                afr[g][cc] = *(const bf16x8*)(
                    &EX[imA * 24576 + (k0 >> 6) * 12288 + bswz(px, (k0 & 63) * 2)]);
            }
        }
    }
    __syncthreads();   // all Xs reads done before Es writes

    // software pipeline over 10 rounds
    uint4 pvA[2][6], pvB[2][6];
#pragma unroll
    for (int q = 0; q < 6; ++q)
        pvA[0][q] = *(const uint4*)(wsb + offb[q]);
#pragma unroll
    for (int q = 0; q < 6; ++q)
        pvB[0][q] = *(const uint4*)(wsb + offb[6 + q]);

#pragma unroll
    for (int di = 0; di < 10; ++di) {
        const int cur = di & 1, nxt = cur ^ 1;
        if (di < 9) {
#pragma unroll
            for (int q = 0; q < 6; ++q)
                pvA[nxt][q] = *(const uint4*)(wsb + offb[q] + (di + 1) * 1536);
        }

        const int hs = h - 4 + di;
        const int zrowok = ((unsigned)hs < 96u);
        float zv[3];
#pragma unroll
        for (int g = 0; g < 3; ++g)
            zv[g] = *(const float*)(wsb + (zrowok ? offz[g] + di * 384
                                                  : (int)ZP_OFF));

        f32x4 ac[3];
#pragma unroll
        for (int g = 0; g < 3; ++g) ac[g] = (f32x4){0.f, 0.f, 0.f, 0.f};

        if (zrowok) {     // block-uniform: skip MFMA for pad rows
#pragma unroll
            for (int cc = 0; cc < 4; ++cc)
#pragma unroll
                for (int g = 0; g < 3; ++g) {
                    union { uint4 u; bf16x8 f; } cv;
                    cv.u = (cc < 2) ? pvA[cur][cc * 3 + g]
                                    : pvB[cur][(cc - 2) * 3 + g];
                    ac[g] = __builtin_amdgcn_mfma_f32_16x16x32_bf16(
                        afr[g][cc], cv.f, ac[g], 0, 0, 0);
                }
        }

        // band extract: plane = hi>>1 (image row h / h+1), shift-row di-plane
        {
            const int imw = hi >> 1;
            const int rnd = di - imw;
            if ((unsigned)rnd < 9u) {
#pragma unroll
                for (int g = 0; g < 3; ++g) {
                    const int uu = wv * 3 + g;
#pragma unroll
                    for (int reg = 0; reg < 4; ++reg) {
                        const int ip = (hi & 1) * 4 + reg;   // px-in-group 0..7
                        const int dji = li - ip;
                        if (dji >= 0 && dji <= 8)
                            Es[(imw * 81 + rnd * 9 + dji) * ESW + uu * 8 + ip] =
                                (ac[g][reg] + zv[g]) * SCALE;
                    }
                }
            }
        }

        if (di < 9) {
#pragma unroll
            for (int q = 0; q < 6; ++q)
                pvB[nxt][q] = *(const uint4*)(wsb + offb[6 + q] + (di + 1) * 1536);
        }
    }

    __syncthreads();
    // bulk coalesced store: 2 rows x 81 shift-planes x 96 w
    const size_t ob = (size_t)b * 81 * HW + (size_t)h * 96;
    for (int idx = t; idx < 2 * 81 * 96; idx += 256) {
        int p = idx / (81 * 96);
        int r2 = idx - p * (81 * 96);
        int s = r2 / 96, w = r2 - s * 96;
        out[ob + (size_t)s * HW + p * 96 + w] = Es[(p * 81 + s) * ESW + w];
    }
}

// ---------------- host ------------------------------------------------------
extern "C" void kernel_launch(void* const* d_in, const int* in_sizes, int n_in,
                              void* d_out, int out_size, void* d_ws, size_t ws_size,
                              hipStream_t stream) {
    const float* input1 = (const float*)d_in[0];
    const float* input2 = (const float*)d_in[1];
    const float* proj_w = (const float*)d_in[2];
    const float* proj_b = (const float*)d_in[3];
    float* out = (float*)d_out;

    char* ws = (char*)d_ws;
    if (ws_size < WS_NEED) return;  // fail loudly (output stays poisoned)

    unsigned short* Abuf = (unsigned short*)(ws + AB_OFF);
    float* vbuf = (float*)(ws + V_OFF);
    float* sbuf = (float*)(ws + S_OFF);
    unsigned short* y2 = (unsigned short*)(ws + Y2_OFF);
    float* z2 = (float*)(ws + Z2_OFF);
    char* zp = ws + ZP_OFF;

    k1_prep<<<dim3(144), dim3(128), 0, stream>>>(proj_w, proj_b, Abuf, vbuf, sbuf, zp);
    k2_proj<<<dim3(2304), dim3(512), 0, stream>>>(input2, Abuf, vbuf, sbuf, y2, z2);
    k3_corr<<<dim3(48, 32), dim3(256), 0, stream>>>(input1, ws, out);
}